// Round 1
// baseline (56.970 us; speedup 1.0000x reference)
//
#include <hip/hip_runtime.h>

// QuantumSubgenerator closed form.
//
// Circuit: RY(latent)⊗RY(w0) on |0..0> -> product state, per-qubit angle
// theta_j = latent[b,j] + w0[j].  CNOT ring (0->1,...,10->11,11->0) is a
// GF(2)-linear basis permutation M.  Final RY(w1) layer pushed through Z
// (Heisenberg): <Z_q>_out = cos(w1_q)<Z_q>_mid - sin(w1_q)<X_q>_mid.
// On the permuted product state both factorize:
//   <Z_q>_mid = prod_{j in S_q} cos(theta_j),  S_0={1..11}, S_q={0..q} (q>=1)
//   <X_q>_mid = prod_{j in T_q} sin(theta_j),  T_0={0,1}, T_q={q,q+1} (1<=q<=10),
//                                              T_11={0,1,11}
// (S_q = row support of M; T_q = support of M^{-1} e_q; verified by hand on n=3.)

#define BATCH 1024
#define NQ 12

__global__ __launch_bounds__(256) void qsub_closed_form(
    const float* __restrict__ latent,   // (1024, 12)
    const float* __restrict__ weights,  // (2, 12): row 0 = w0, row 1 = w1
    float* __restrict__ out)            // (1024, 12)
{
    const int b = blockIdx.x * blockDim.x + threadIdx.x;
    if (b >= BATCH) return;

    const float* lat = latent + b * NQ;

    float ct[NQ], st[NQ];
#pragma unroll
    for (int j = 0; j < NQ; ++j) {
        const float th = lat[j] + weights[j];       // theta_j = latent + w0
        sincosf(th, &st[j], &ct[j]);
    }

    // prefix products of cos(theta): P[q] = prod_{j=0..q} ct[j]
    float P[NQ];
    P[0] = ct[0];
#pragma unroll
    for (int j = 1; j < NQ; ++j) P[j] = P[j - 1] * ct[j];

    // tail = prod_{j=1..11} ct[j]   (Z_mid for qubit 0)
    float tail = 1.0f;
#pragma unroll
    for (int j = 1; j < NQ; ++j) tail *= ct[j];

    float zmid[NQ], xmid[NQ];
    zmid[0] = tail;
#pragma unroll
    for (int q = 1; q < NQ; ++q) zmid[q] = P[q];

    xmid[0] = st[0] * st[1];
#pragma unroll
    for (int q = 1; q < NQ - 1; ++q) xmid[q] = st[q] * st[q + 1];
    xmid[NQ - 1] = st[0] * st[1] * st[NQ - 1];

    float* o = out + b * NQ;
#pragma unroll
    for (int q = 0; q < NQ; ++q) {
        const float w1 = weights[NQ + q];
        float sw, cw;
        sincosf(w1, &sw, &cw);
        o[q] = cw * zmid[q] - sw * xmid[q];
    }
}

extern "C" void kernel_launch(void* const* d_in, const int* in_sizes, int n_in,
                              void* d_out, int out_size, void* d_ws, size_t ws_size,
                              hipStream_t stream) {
    const float* latent  = (const float*)d_in[0];   // (1024, 12) fp32
    const float* weights = (const float*)d_in[1];   // (2, 12)   fp32
    float* out = (float*)d_out;                     // (1024, 12) fp32

    qsub_closed_form<<<BATCH / 256, 256, 0, stream>>>(latent, weights, out);
}

// Round 2
// 54.450 us; speedup vs baseline: 1.0463x; 1.0463x over previous
//
#include <hip/hip_runtime.h>

// QuantumSubgenerator closed form (see round-1 derivation):
//   theta_j = latent[b,j] + w0[j]  (RY∘RY on |0..0> -> product state)
//   CNOT ring = GF(2)-linear basis permutation M
//   <Z_q>_out = cos(w1_q)*Z_mid[q] - sin(w1_q)*X_mid[q]
//   Z_mid[0] = prod_{j=1..11} cos(theta_j); Z_mid[q>=1] = prod_{j=0..q} cos(theta_j)
//   X_mid[0] = s0*s1; X_mid[q=1..10] = s_q*s_{q+1}; X_mid[11] = s0*s1*s11
//
// Round 2: native __sinf/__cosf (v_sin_f32/v_cos_f32; angles are ~N(0,1.1),
// error ~1e-5 << 2e-2 threshold), float4 row I/O, 64-thread blocks over 16
// blocks to spread the latency chain across more CUs.

#define BATCH 1024
#define NQ 12

__global__ __launch_bounds__(64) void qsub_closed_form(
    const float* __restrict__ latent,   // (1024, 12)
    const float* __restrict__ weights,  // (2, 12): row 0 = w0, row 1 = w1
    float* __restrict__ out)            // (1024, 12)
{
    const int b = blockIdx.x * blockDim.x + threadIdx.x;

    // Row is 48 B, 16B-aligned -> 3x float4.
    const float4* lat4 = (const float4*)(latent + b * NQ);
    float4 l0 = lat4[0], l1 = lat4[1], l2 = lat4[2];
    float th[NQ] = {l0.x, l0.y, l0.z, l0.w, l1.x, l1.y, l1.z, l1.w,
                    l2.x, l2.y, l2.z, l2.w};

    float ct[NQ], st[NQ];
#pragma unroll
    for (int j = 0; j < NQ; ++j) {
        const float t = th[j] + weights[j];   // + w0[j]
        st[j] = __sinf(t);
        ct[j] = __cosf(t);
    }

    // Prefix products of cos: P[q] = prod_{0..q} ct
    float P[NQ];
    P[0] = ct[0];
#pragma unroll
    for (int j = 1; j < NQ; ++j) P[j] = P[j - 1] * ct[j];

    // tail = prod_{1..11} ct  (Z_mid for qubit 0)
    float tail = 1.0f;
#pragma unroll
    for (int j = 1; j < NQ; ++j) tail *= ct[j];

    float zmid[NQ], xmid[NQ];
    zmid[0] = tail;
#pragma unroll
    for (int q = 1; q < NQ; ++q) zmid[q] = P[q];

    xmid[0] = st[0] * st[1];
#pragma unroll
    for (int q = 1; q < NQ - 1; ++q) xmid[q] = st[q] * st[q + 1];
    xmid[NQ - 1] = st[0] * st[1] * st[NQ - 1];

    float o[NQ];
#pragma unroll
    for (int q = 0; q < NQ; ++q) {
        const float w1 = weights[NQ + q];
        o[q] = __cosf(w1) * zmid[q] - __sinf(w1) * xmid[q];
    }

    float4* out4 = (float4*)(out + b * NQ);
    out4[0] = make_float4(o[0], o[1], o[2], o[3]);
    out4[1] = make_float4(o[4], o[5], o[6], o[7]);
    out4[2] = make_float4(o[8], o[9], o[10], o[11]);
}

extern "C" void kernel_launch(void* const* d_in, const int* in_sizes, int n_in,
                              void* d_out, int out_size, void* d_ws, size_t ws_size,
                              hipStream_t stream) {
    const float* latent  = (const float*)d_in[0];   // (1024, 12) fp32
    const float* weights = (const float*)d_in[1];   // (2, 12)   fp32
    float* out = (float*)d_out;                     // (1024, 12) fp32

    qsub_closed_form<<<BATCH / 64, 64, 0, stream>>>(latent, weights, out);
}